// Round 6
// baseline (200.780 us; speedup 1.0000x reference)
//
#include <hip/hip_runtime.h>

// ALiBi positional bias, fp32:
//   out[b,h,i,j] = in[b,h,i,j] - slope[h] * |j - i|
// B=2, H=16, S=2048; slope[h] = 2^{-0.5*(h+1)} (H=16 pow2, exact).
//
// R5: identical structure to R4 (block-contiguous 16 rows / 128 KiB per
// block, scalar slope/i_base, depth-2 register pipeline) but with ALL
// non-temporal hints removed — A/B isolating NT. Mechanism under test:
// NT stores bypass L2 write-combining; the harness's fill kernels use
// plain stores and sustain 6.6-6.8 TB/s write BW.

typedef float f32x4 __attribute__((ext_vector_type(4)));

__device__ __forceinline__ void apply4(f32x4& v, float d, float ns) {
    v.x = fmaf(ns, fabsf(d),        v.x);
    v.y = fmaf(ns, fabsf(d + 1.0f), v.y);
    v.z = fmaf(ns, fabsf(d + 2.0f), v.z);
    v.w = fmaf(ns, fabsf(d + 3.0f), v.w);
}

__global__ __launch_bounds__(256) void alibi_bias_kernel(
    const float* __restrict__ in, float* __restrict__ out) {
    const int i_base = (blockIdx.x << 4) & 2047;        // first row i of block
    const int h      = (blockIdx.x >> 7) & 15;          // head index
    const float nslope = -exp2f(-0.5f * (float)(h + 1));

    const long long base4 = (long long)blockIdx.x << 13; // 8192 float4s/block
    const f32x4* __restrict__ in4  = reinterpret_cast<const f32x4*>(in)  + base4;
    f32x4* __restrict__       out4 = reinterpret_cast<f32x4*>(out) + base4;

    const int tid = threadIdx.x;

    // Prologue: batches 0 and 1 in flight.
    f32x4 a0 = in4[tid];
    f32x4 a1 = in4[tid + 256];
    f32x4 a2 = in4[tid + 512];
    f32x4 a3 = in4[tid + 768];
    f32x4 b0 = in4[tid + 1024];
    f32x4 b1 = in4[tid + 1280];
    f32x4 b2 = in4[tid + 1536];
    f32x4 b3 = in4[tid + 1792];

    float d = (float)((tid << 2) - i_base);  // distance base, batch 0

#pragma unroll
    for (int it = 0; it < 8; ++it) {
        f32x4 c0, c1, c2, c3;
        if (it < 6) {
            int l = ((it + 2) << 10) + tid;
            c0 = in4[l];
            c1 = in4[l + 256];
            c2 = in4[l + 512];
            c3 = in4[l + 768];
        }

        apply4(a0, d,           nslope);   // row 2*it,   cols 4*tid
        apply4(a1, d + 1024.0f, nslope);   // row 2*it,   cols 4*tid+1024
        apply4(a2, d - 1.0f,    nslope);   // row 2*it+1, cols 4*tid
        apply4(a3, d + 1023.0f, nslope);   // row 2*it+1, cols 4*tid+1024

        int s = (it << 10) + tid;
        out4[s]       = a0;
        out4[s + 256] = a1;
        out4[s + 512] = a2;
        out4[s + 768] = a3;

        a0 = b0; a1 = b1; a2 = b2; a3 = b3;
        b0 = c0; b1 = c1; b2 = c2; b3 = c3;
        d -= 2.0f;
    }
}

extern "C" void kernel_launch(void* const* d_in, const int* in_sizes, int n_in,
                              void* d_out, int out_size, void* d_ws, size_t ws_size,
                              hipStream_t stream) {
    const float* in = (const float*)d_in[0];
    float* out = (float*)d_out;

    long long n4 = (long long)out_size >> 2;   // 2^25 float4s
    int grid = (int)(n4 >> 13);                // 8192 float4s per block -> 4096

    alibi_bias_kernel<<<grid, 256, 0, stream>>>(in, out);
}

// Round 7
// 188.059 us; speedup vs baseline: 1.0676x; 1.0676x over previous
//
#include <hip/hip_runtime.h>

// ALiBi positional bias, fp32:
//   out[b,h,i,j] = in[b,h,i,j] - slope[h] * |j - i|
// B=2, H=16, S=2048; slope[h] = 2^{-0.5*(h+1)} (H=16 pow2, exact).
//
// R6 = exact revert to R4 (best: 188.2 us, 5.70 TB/s mixed, 90.6% of
// measured copy ceiling). R5's A/B proved NT hints are +6.7% — keep.
// Structure: block owns 16 rows (128 KiB contiguous); slope / i_base
// block-uniform scalars; depth-2 register pipeline (8 NT loads in
// flight); distance base strength-reduced to d -= 2 per iteration.

typedef float f32x4 __attribute__((ext_vector_type(4)));

__device__ __forceinline__ void apply4(f32x4& v, float d, float ns) {
    v.x = fmaf(ns, fabsf(d),        v.x);
    v.y = fmaf(ns, fabsf(d + 1.0f), v.y);
    v.z = fmaf(ns, fabsf(d + 2.0f), v.z);
    v.w = fmaf(ns, fabsf(d + 3.0f), v.w);
}

__global__ __launch_bounds__(256) void alibi_bias_kernel(
    const float* __restrict__ in, float* __restrict__ out) {
    const int i_base = (blockIdx.x << 4) & 2047;        // first row i of block
    const int h      = (blockIdx.x >> 7) & 15;          // head index
    const float nslope = -exp2f(-0.5f * (float)(h + 1));

    const long long base4 = (long long)blockIdx.x << 13; // 8192 float4s/block
    const f32x4* __restrict__ in4  = reinterpret_cast<const f32x4*>(in)  + base4;
    f32x4* __restrict__       out4 = reinterpret_cast<f32x4*>(out) + base4;

    const int tid = threadIdx.x;

    // Prologue: batches 0 and 1 in flight.
    f32x4 a0 = __builtin_nontemporal_load(&in4[tid]);
    f32x4 a1 = __builtin_nontemporal_load(&in4[tid + 256]);
    f32x4 a2 = __builtin_nontemporal_load(&in4[tid + 512]);
    f32x4 a3 = __builtin_nontemporal_load(&in4[tid + 768]);
    f32x4 b0 = __builtin_nontemporal_load(&in4[tid + 1024]);
    f32x4 b1 = __builtin_nontemporal_load(&in4[tid + 1280]);
    f32x4 b2 = __builtin_nontemporal_load(&in4[tid + 1536]);
    f32x4 b3 = __builtin_nontemporal_load(&in4[tid + 1792]);

    float d = (float)((tid << 2) - i_base);  // distance base, batch 0

#pragma unroll
    for (int it = 0; it < 8; ++it) {
        f32x4 c0, c1, c2, c3;
        if (it < 6) {
            // Prefetch batch it+2: consumed loads get a full extra
            // iteration of slack past the store drain.
            int l = ((it + 2) << 10) + tid;
            c0 = __builtin_nontemporal_load(&in4[l]);
            c1 = __builtin_nontemporal_load(&in4[l + 256]);
            c2 = __builtin_nontemporal_load(&in4[l + 512]);
            c3 = __builtin_nontemporal_load(&in4[l + 768]);
        }

        apply4(a0, d,           nslope);   // row 2*it,   cols 4*tid
        apply4(a1, d + 1024.0f, nslope);   // row 2*it,   cols 4*tid+1024
        apply4(a2, d - 1.0f,    nslope);   // row 2*it+1, cols 4*tid
        apply4(a3, d + 1023.0f, nslope);   // row 2*it+1, cols 4*tid+1024

        int s = (it << 10) + tid;
        __builtin_nontemporal_store(a0, &out4[s]);
        __builtin_nontemporal_store(a1, &out4[s + 256]);
        __builtin_nontemporal_store(a2, &out4[s + 512]);
        __builtin_nontemporal_store(a3, &out4[s + 768]);

        a0 = b0; a1 = b1; a2 = b2; a3 = b3;
        b0 = c0; b1 = c1; b2 = c2; b3 = c3;
        d -= 2.0f;
    }
}

extern "C" void kernel_launch(void* const* d_in, const int* in_sizes, int n_in,
                              void* d_out, int out_size, void* d_ws, size_t ws_size,
                              hipStream_t stream) {
    const float* in = (const float*)d_in[0];
    float* out = (float*)d_out;

    long long n4 = (long long)out_size >> 2;   // 2^25 float4s
    int grid = (int)(n4 >> 13);                // 8192 float4s per block -> 4096

    alibi_bias_kernel<<<grid, 256, 0, stream>>>(in, out);
}